// Round 5
// baseline (498.821 us; speedup 1.0000x reference)
//
#include <hip/hip_runtime.h>
#include <hip/hip_bf16.h>

#define BATCH 8
#define SEQ   2048
#define DIM   512
#define QB    64
#define KB    64
#define NT    512          // 8 waves
#define NKV   (SEQ / KB)   // 32 KV tiles

typedef __attribute__((ext_vector_type(8))) short short8;
typedef __attribute__((ext_vector_type(4))) float f32x4;
typedef __attribute__((ext_vector_type(4))) unsigned short ushort4v;

__device__ __forceinline__ unsigned short f2bf(float f) {
    union { float f; unsigned u; } v; v.f = f;
    return (unsigned short)((v.u + 0x7FFFu + ((v.u >> 16) & 1u)) >> 16);
}

// Row swizzle for the K/V tile. All terms multiples of 8 => any 8-aligned
// 8-element read strip stays contiguous after XOR. The 16*((kv>>3)&3) term
// spreads the PV gather's 4 lane-groups (which differ only in kv>>3) across
// distinct bank dwords -> gather is ~conflict-free (R4: conflicts 1.73e7->4.2e6).
__device__ __forceinline__ int swz(int kv) {
    return (8 * (kv & 7)) ^ (16 * ((kv >> 3) & 3)) ^ (64 * ((kv >> 3) & 1));
}

// score = X·X^T (no scaling), softmax, out = P·X   — flash-style, bf16 MFMA
// launch_bounds(NT, 1): R4 regression root-cause was (NT,2) capping VGPR at 128
// (interpreted as 2 blocks/CU -> 4 waves/SIMD) while qfrag alone needs 128 ->
// massive scratch spill (FETCH 312MB). min=1 restores the 256-VGPR budget; HW
// occupancy is LDS-capped at 1 block/CU either way.
__global__ __launch_bounds__(NT, 1)
void attn_fwd(const float* __restrict__ X, float* __restrict__ O) {
    const int b   = blockIdx.x & 7;          // batch -> XCD pinning
    const int qt  = blockIdx.x >> 3;
    const int tid = threadIdx.x;
    const int lane = tid & 63;
    const int w    = tid >> 6;
    const int col  = lane & 15;
    const int kgrp = lane >> 4;

    __shared__ alignas(16) unsigned short Klds[KB * DIM];       // 64 KB, swizzled
    __shared__ alignas(16) float Sbuf[QB][KB + 4];              // 17 KB
    __shared__ alignas(16) unsigned short Pfrag[4][2][64][8];   // 8 KB, A-frag layout
    __shared__ float m_s[QB], l_s[QB], fac_s[QB];

    const float* Xb = X + (size_t)b * SEQ * DIM;

    // ---- Q preload: wave w owns 32 q-rows (half qh), kv-strip kc (16 wide)
    const int qh = w >> 2;       // 0..1
    const int kc = w & 3;        // 0..3
    short8 qfrag[2][16];         // 128 VGPR
    #pragma unroll
    for (int qq = 0; qq < 2; ++qq) {
        const int qrow = qt * QB + qh * 32 + qq * 16 + col;
        const float* qp = Xb + (size_t)qrow * DIM;
        #pragma unroll
        for (int ks = 0; ks < 16; ++ks) {
            const int d0 = ks * 32 + kgrp * 8;
            float4 a = *(const float4*)(qp + d0);
            float4 c = *(const float4*)(qp + d0 + 4);
            short8 q8;
            q8[0] = f2bf(a.x); q8[1] = f2bf(a.y); q8[2] = f2bf(a.z); q8[3] = f2bf(a.w);
            q8[4] = f2bf(c.x); q8[5] = f2bf(c.y); q8[6] = f2bf(c.z); q8[7] = f2bf(c.w);
            qfrag[qq][ks] = q8;
        }
    }

    if (tid < QB) { m_s[tid] = -INFINITY; l_s[tid] = 0.f; }

    f32x4 oacc[4][4];   // O[64 q][w*64 .. +64 d] : [q2][dt]
    #pragma unroll
    for (int i = 0; i < 4; ++i)
        #pragma unroll
        for (int j = 0; j < 4; ++j)
            oacc[i][j] = (f32x4){0.f, 0.f, 0.f, 0.f};

    for (int t = 0; t < NKV; ++t) {
        __syncthreads();   // (a) prev readers done
        // ---- stage KV tile (fp32 -> bf16, swizzled); wave-coalesced 1KB rows
        {
            const float* kp = Xb + (size_t)(t * KB) * DIM;
            #pragma unroll 4
            for (int it = 0; it < 16; ++it) {
                const int idx = it * NT + tid;
                const int kv  = idx >> 7;
                const int d0  = (idx & 127) * 4;
                float4 v = *(const float4*)(kp + (size_t)kv * DIM + d0);
                ushort4v h;
                h[0] = f2bf(v.x); h[1] = f2bf(v.y); h[2] = f2bf(v.z); h[3] = f2bf(v.w);
                *(ushort4v*)&Klds[kv * DIM + (d0 ^ swz(kv))] = h;
            }
        }
        __syncthreads();   // (b) tile ready

        // ---- QK^T: wave computes S[qh*32 .. +32][kc*16 .. +16]; 1 K-read -> 2 MFMA
        {
            const int kvrow = kc * 16 + col;
            const unsigned short* kbase = &Klds[kvrow * DIM];
            const int sw = swz(kvrow);
            f32x4 sacc0 = (f32x4){0.f,0.f,0.f,0.f};
            f32x4 sacc1 = (f32x4){0.f,0.f,0.f,0.f};
            #pragma unroll
            for (int ks = 0; ks < 16; ++ks) {
                short8 kfr = *(const short8*)(kbase + ((ks * 32 + kgrp * 8) ^ sw));
                sacc0 = __builtin_amdgcn_mfma_f32_16x16x32_bf16(qfrag[0][ks], kfr, sacc0, 0, 0, 0);
                sacc1 = __builtin_amdgcn_mfma_f32_16x16x32_bf16(qfrag[1][ks], kfr, sacc1, 0, 0, 0);
            }
            #pragma unroll
            for (int r = 0; r < 4; ++r) {
                Sbuf[qh * 32 + 0  + kgrp * 4 + r][kc * 16 + col] = sacc0[r];
                Sbuf[qh * 32 + 16 + kgrp * 4 + r][kc * 16 + col] = sacc1[r];
            }
        }
        __syncthreads();   // (c) Sbuf ready

        // ---- online softmax (8 threads/row) + P staged in MFMA A-frag layout
        {
            const int r = tid >> 3;
            const int c = tid & 7;
            float4 sa = *(const float4*)&Sbuf[r][c * 8];
            float4 sb = *(const float4*)&Sbuf[r][c * 8 + 4];
            float mloc = fmaxf(fmaxf(fmaxf(sa.x, sa.y), fmaxf(sa.z, sa.w)),
                               fmaxf(fmaxf(sb.x, sb.y), fmaxf(sb.z, sb.w)));
            mloc = fmaxf(mloc, __shfl_xor(mloc, 1));
            mloc = fmaxf(mloc, __shfl_xor(mloc, 2));
            mloc = fmaxf(mloc, __shfl_xor(mloc, 4));
            const float mold = m_s[r];
            const float mnew = fmaxf(mold, mloc);
            const float fac  = __expf(mold - mnew);   // exp(-inf)=0 on first tile
            float p0 = __expf(sa.x - mnew), p1 = __expf(sa.y - mnew);
            float p2 = __expf(sa.z - mnew), p3 = __expf(sa.w - mnew);
            float p4 = __expf(sb.x - mnew), p5 = __expf(sb.y - mnew);
            float p6 = __expf(sb.z - mnew), p7 = __expf(sb.w - mnew);
            float lsum = ((p0 + p1) + (p2 + p3)) + ((p4 + p5) + (p6 + p7));
            lsum += __shfl_xor(lsum, 1);
            lsum += __shfl_xor(lsum, 2);
            lsum += __shfl_xor(lsum, 4);
            short8 p8;
            p8[0] = f2bf(p0); p8[1] = f2bf(p1); p8[2] = f2bf(p2); p8[3] = f2bf(p3);
            p8[4] = f2bf(p4); p8[5] = f2bf(p5); p8[6] = f2bf(p6); p8[7] = f2bf(p7);
            // value (q=r, kv=8c+j) -> Pfrag[r>>4][c>>2][(r&15)+16*(c&3)][j]
            *(short8*)&Pfrag[r >> 4][c >> 2][(r & 15) + 16 * (c & 3)][0] = p8;
            if (c == 0) {
                m_s[r] = mnew;
                fac_s[r] = fac;
                l_s[r] = l_s[r] * fac + lsum;
            }
        }
        __syncthreads();   // (d) Pfrag/fac ready

        // ---- rescale O, then PV: A from Pfrag (lane-contig b128), B via gather
        #pragma unroll
        for (int q2 = 0; q2 < 4; ++q2) {
            #pragma unroll
            for (int r = 0; r < 4; ++r) {
                const float f = fac_s[q2 * 16 + kgrp * 4 + r];
                #pragma unroll
                for (int dt = 0; dt < 4; ++dt) oacc[q2][dt][r] *= f;
            }
        }
        #pragma unroll
        for (int kc2 = 0; kc2 < 2; ++kc2) {
            const int kvb = kc2 * 32 + kgrp * 8;
            short8 afr[4];
            #pragma unroll
            for (int q2 = 0; q2 < 4; ++q2)
                afr[q2] = *(const short8*)&Pfrag[q2][kc2][lane][0];
            // bfr gathered per-dt and consumed immediately (live regs 16 -> 4)
            #pragma unroll
            for (int dt = 0; dt < 4; ++dt) {
                const int d = w * 64 + dt * 16 + col;
                short8 bfr;
                #pragma unroll
                for (int j = 0; j < 8; ++j) {
                    const int kv = kvb + j;
                    bfr[j] = (short)Klds[kv * DIM + (d ^ swz(kv))];
                }
                #pragma unroll
                for (int q2 = 0; q2 < 4; ++q2)
                    oacc[q2][dt] = __builtin_amdgcn_mfma_f32_16x16x32_bf16(afr[q2], bfr, oacc[q2][dt], 0, 0, 0);
            }
        }
    }

    // ---- epilogue: divide by l, store fp32
    #pragma unroll
    for (int q2 = 0; q2 < 4; ++q2) {
        #pragma unroll
        for (int r = 0; r < 4; ++r) {
            const int row = q2 * 16 + kgrp * 4 + r;
            const float inv = 1.f / l_s[row];
            float* op = O + ((size_t)b * SEQ + qt * QB + row) * DIM + w * 64 + col;
            #pragma unroll
            for (int dt = 0; dt < 4; ++dt)
                op[dt * 16] = oacc[q2][dt][r] * inv;
        }
    }
}

extern "C" void kernel_launch(void* const* d_in, const int* in_sizes, int n_in,
                              void* d_out, int out_size, void* d_ws, size_t ws_size,
                              hipStream_t stream) {
    const float* X = (const float*)d_in[0];
    float* Out = (float*)d_out;
    dim3 grid(BATCH * (SEQ / QB));   // 256 blocks = 1 per CU
    dim3 block(NT);
    hipLaunchKernelGGL(attn_fwd, grid, block, 0, stream, X, Out);
}

// Round 6
// 246.442 us; speedup vs baseline: 2.0241x; 2.0241x over previous
//
#include <hip/hip_runtime.h>
#include <hip/hip_bf16.h>

#define BATCH 8
#define SEQ   2048
#define DIM   512
#define QB    64
#define KB    64
#define NT    512          // 8 waves
#define NKV   (SEQ / KB)   // 32 KV tiles

typedef __attribute__((ext_vector_type(8))) short short8;
typedef __attribute__((ext_vector_type(4))) float f32x4;
typedef __attribute__((ext_vector_type(4))) unsigned short ushort4v;

__device__ __forceinline__ unsigned short f2bf(float f) {
    union { float f; unsigned u; } v; v.f = f;
    return (unsigned short)((v.u + 0x7FFFu + ((v.u >> 16) & 1u)) >> 16);
}

// Row swizzle for the K/V tile. All terms multiples of 8 => any 8-aligned
// 8-element strip stays contiguous after XOR. The 16*((kv>>3)&3) term spreads
// the PV gather's 4 lane-groups (which differ only in kv>>3) across distinct
// bank dwords (validated R4/R5: conflicts 1.73e7 -> 4.2e6).
__device__ __forceinline__ int swz(int kv) {
    return (8 * (kv & 7)) ^ (16 * ((kv >> 3) & 3)) ^ (64 * ((kv >> 3) & 1));
}

// score = X·X^T (no scaling), softmax, out = P·X   — flash-style, bf16 MFMA.
// R2-proven register envelope: 16 q-rows/wave (qfrag[16] = 64 VGPR), bounds
// (NT,2) = R2's known-good allocation. R4/R5 showed 32 q-rows/wave spills
// (compiler caps arch VGPR at 128 for 8-wave blocks regardless of bounds).
__global__ __launch_bounds__(NT, 2)
void attn_fwd(const float* __restrict__ X, float* __restrict__ O) {
    const int b   = blockIdx.x & 7;          // batch -> XCD pinning
    const int qt  = blockIdx.x >> 3;
    const int tid = threadIdx.x;
    const int lane = tid & 63;
    const int w    = tid >> 6;
    const int col  = lane & 15;
    const int kgrp = lane >> 4;

    __shared__ alignas(16) unsigned short Klds[KB * DIM];       // 64 KB, swizzled
    __shared__ alignas(16) float Sbuf[QB][KB + 4];              // 17 KB
    __shared__ alignas(16) unsigned short Pfrag[4][2][64][8];   // 8 KB, A-frag layout
    __shared__ float m_s[QB], l_s[QB], fac_s[QB];

    const float* Xb = X + (size_t)b * SEQ * DIM;

    // ---- Q preload: wave w owns 16 q-rows (strip qs), kc strips kc0..kc0+1
    const int qs  = w >> 1;      // 0..3
    const int kc0 = (w & 1) * 2; // 0 or 2
    short8 qfrag[16];            // 64 VGPR
    {
        const int qrow = qt * QB + qs * 16 + col;
        const float* qp = Xb + (size_t)qrow * DIM;
        #pragma unroll
        for (int ks = 0; ks < 16; ++ks) {
            const int d0 = ks * 32 + kgrp * 8;
            float4 a = *(const float4*)(qp + d0);
            float4 c = *(const float4*)(qp + d0 + 4);
            short8 q8;
            q8[0] = f2bf(a.x); q8[1] = f2bf(a.y); q8[2] = f2bf(a.z); q8[3] = f2bf(a.w);
            q8[4] = f2bf(c.x); q8[5] = f2bf(c.y); q8[6] = f2bf(c.z); q8[7] = f2bf(c.w);
            qfrag[ks] = q8;
        }
    }

    if (tid < QB) { m_s[tid] = -INFINITY; l_s[tid] = 0.f; }

    f32x4 oacc[4][4];   // O[64 q][w*64 .. +64 d] : [q2][dt]
    #pragma unroll
    for (int i = 0; i < 4; ++i)
        #pragma unroll
        for (int j = 0; j < 4; ++j)
            oacc[i][j] = (f32x4){0.f, 0.f, 0.f, 0.f};

    for (int t = 0; t < NKV; ++t) {
        __syncthreads();   // (a) prev readers done
        // ---- stage KV tile (fp32 -> bf16, swizzled); wave-coalesced 1KB rows
        {
            const float* kp = Xb + (size_t)(t * KB) * DIM;
            #pragma unroll 4
            for (int it = 0; it < 16; ++it) {
                const int idx = it * NT + tid;
                const int kv  = idx >> 7;
                const int d0  = (idx & 127) * 4;
                float4 v = *(const float4*)(kp + (size_t)kv * DIM + d0);
                ushort4v h;
                h[0] = f2bf(v.x); h[1] = f2bf(v.y); h[2] = f2bf(v.z); h[3] = f2bf(v.w);
                *(ushort4v*)&Klds[kv * DIM + (d0 ^ swz(kv))] = h;
            }
        }
        __syncthreads();   // (b) tile ready

        // ---- QK^T: wave computes S[qs*16 .. +16][kc0*16 .. +32]
        #pragma unroll
        for (int i = 0; i < 2; ++i) {
            const int kc = kc0 + i;
            const int kvrow = kc * 16 + col;
            const unsigned short* kbase = &Klds[kvrow * DIM];
            const int sw = swz(kvrow);
            f32x4 sacc = (f32x4){0.f,0.f,0.f,0.f};
            #pragma unroll
            for (int ks = 0; ks < 16; ++ks) {
                short8 kfr = *(const short8*)(kbase + ((ks * 32 + kgrp * 8) ^ sw));
                sacc = __builtin_amdgcn_mfma_f32_16x16x32_bf16(qfrag[ks], kfr, sacc, 0, 0, 0);
            }
            #pragma unroll
            for (int r = 0; r < 4; ++r)
                Sbuf[qs * 16 + kgrp * 4 + r][kc * 16 + col] = sacc[r];
        }
        __syncthreads();   // (c) Sbuf ready

        // ---- online softmax (8 threads/row) + P staged in MFMA A-frag layout
        {
            const int r = tid >> 3;
            const int c = tid & 7;
            float4 sa = *(const float4*)&Sbuf[r][c * 8];
            float4 sb = *(const float4*)&Sbuf[r][c * 8 + 4];
            float mloc = fmaxf(fmaxf(fmaxf(sa.x, sa.y), fmaxf(sa.z, sa.w)),
                               fmaxf(fmaxf(sb.x, sb.y), fmaxf(sb.z, sb.w)));
            mloc = fmaxf(mloc, __shfl_xor(mloc, 1));
            mloc = fmaxf(mloc, __shfl_xor(mloc, 2));
            mloc = fmaxf(mloc, __shfl_xor(mloc, 4));
            const float mold = m_s[r];
            const float mnew = fmaxf(mold, mloc);
            const float fac  = __expf(mold - mnew);   // exp(-inf)=0 on first tile
            float p0 = __expf(sa.x - mnew), p1 = __expf(sa.y - mnew);
            float p2 = __expf(sa.z - mnew), p3 = __expf(sa.w - mnew);
            float p4 = __expf(sb.x - mnew), p5 = __expf(sb.y - mnew);
            float p6 = __expf(sb.z - mnew), p7 = __expf(sb.w - mnew);
            float lsum = ((p0 + p1) + (p2 + p3)) + ((p4 + p5) + (p6 + p7));
            lsum += __shfl_xor(lsum, 1);
            lsum += __shfl_xor(lsum, 2);
            lsum += __shfl_xor(lsum, 4);
            short8 p8;
            p8[0] = f2bf(p0); p8[1] = f2bf(p1); p8[2] = f2bf(p2); p8[3] = f2bf(p3);
            p8[4] = f2bf(p4); p8[5] = f2bf(p5); p8[6] = f2bf(p6); p8[7] = f2bf(p7);
            // value (q=r, kv=8c+j) -> Pfrag[r>>4][c>>2][(r&15)+16*(c&3)][j]
            *(short8*)&Pfrag[r >> 4][c >> 2][(r & 15) + 16 * (c & 3)][0] = p8;
            if (c == 0) {
                m_s[r] = mnew;
                fac_s[r] = fac;
                l_s[r] = l_s[r] * fac + lsum;
            }
        }
        __syncthreads();   // (d) Pfrag/fac ready

        // ---- rescale O, then PV: A from Pfrag (lane-contig b128), B via gather
        #pragma unroll
        for (int q2 = 0; q2 < 4; ++q2) {
            #pragma unroll
            for (int r = 0; r < 4; ++r) {
                const float f = fac_s[q2 * 16 + kgrp * 4 + r];
                #pragma unroll
                for (int dt = 0; dt < 4; ++dt) oacc[q2][dt][r] *= f;
            }
        }
        #pragma unroll
        for (int kc2 = 0; kc2 < 2; ++kc2) {
            const int kvb = kc2 * 32 + kgrp * 8;
            short8 afr[4];
            #pragma unroll
            for (int q2 = 0; q2 < 4; ++q2)
                afr[q2] = *(const short8*)&Pfrag[q2][kc2][lane][0];
            // bfr gathered per-dt, consumed immediately (4 live regs)
            #pragma unroll
            for (int dt = 0; dt < 4; ++dt) {
                const int d = w * 64 + dt * 16 + col;
                short8 bfr;
                #pragma unroll
                for (int j = 0; j < 8; ++j) {
                    const int kv = kvb + j;
                    bfr[j] = (short)Klds[kv * DIM + (d ^ swz(kv))];
                }
                #pragma unroll
                for (int q2 = 0; q2 < 4; ++q2)
                    oacc[q2][dt] = __builtin_amdgcn_mfma_f32_16x16x32_bf16(afr[q2], bfr, oacc[q2][dt], 0, 0, 0);
            }
        }
    }

    // ---- epilogue: divide by l, store fp32
    #pragma unroll
    for (int q2 = 0; q2 < 4; ++q2) {
        #pragma unroll
        for (int r = 0; r < 4; ++r) {
            const int row = q2 * 16 + kgrp * 4 + r;
            const float inv = 1.f / l_s[row];
            float* op = O + ((size_t)b * SEQ + qt * QB + row) * DIM + w * 64 + col;
            #pragma unroll
            for (int dt = 0; dt < 4; ++dt)
                op[dt * 16] = oacc[q2][dt][r] * inv;
        }
    }
}

extern "C" void kernel_launch(void* const* d_in, const int* in_sizes, int n_in,
                              void* d_out, int out_size, void* d_ws, size_t ws_size,
                              hipStream_t stream) {
    const float* X = (const float*)d_in[0];
    float* Out = (float*)d_out;
    dim3 grid(BATCH * (SEQ / QB));   // 256 blocks = 1 per CU
    dim3 block(NT);
    hipLaunchKernelGGL(attn_fwd, grid, block, 0, stream, X, Out);
}

// Round 7
// 179.649 us; speedup vs baseline: 2.7766x; 1.3718x over previous
//
#include <hip/hip_runtime.h>
#include <hip/hip_bf16.h>

#define BATCH 8
#define SEQ   2048
#define DIM   512
#define QB    32
#define KB    64
#define NT    512          // 8 waves
#define NKV   (SEQ / KB)   // 32 KV tiles

typedef __attribute__((ext_vector_type(8))) short short8;
typedef __attribute__((ext_vector_type(4))) float f32x4;
typedef __attribute__((ext_vector_type(4))) unsigned short ushort4v;

__device__ __forceinline__ unsigned short f2bf(float f) {
    union { float f; unsigned u; } v; v.f = f;
    return (unsigned short)((v.u + 0x7FFFu + ((v.u >> 16) & 1u)) >> 16);
}

// Row swizzle for the K/V tile (validated R4/R5: PV gather conflict-free,
// conflicts 1.73e7 -> 4.2e6). All terms multiples of 8 elems.
__device__ __forceinline__ int swz(int kv) {
    return (8 * (kv & 7)) ^ (16 * ((kv >> 3) & 3)) ^ (64 * ((kv >> 3) & 1));
}

// ---- pre-pass: X fp32 -> bf16 (once per launch, ~8us). Kills the per-tile
// f2bf VALU cost that dominated VALUBusy and halves streamed bytes.
__global__ void to_bf16_kernel(const float* __restrict__ X,
                               unsigned short* __restrict__ Y, int n8) {
    const int i = blockIdx.x * blockDim.x + threadIdx.x;
    if (i >= n8) return;
    const float4 a = ((const float4*)X)[i * 2];
    const float4 b = ((const float4*)X)[i * 2 + 1];
    short8 h;
    h[0] = f2bf(a.x); h[1] = f2bf(a.y); h[2] = f2bf(a.z); h[3] = f2bf(a.w);
    h[4] = f2bf(b.x); h[5] = f2bf(b.y); h[6] = f2bf(b.z); h[7] = f2bf(b.w);
    ((short8*)Y)[i] = h;
}

// score = X·X^T (no scaling), softmax, out = P·X — flash-style, bf16 MFMA.
// QB=32 -> grid 512 -> 2 blocks/CU (LDS 78.7KB): co-resident blocks overlap
// each other's barrier phases (R6 diagnosis: latency/serialization-bound).
__global__ __launch_bounds__(NT, 2)
void attn_fwd(const unsigned short* __restrict__ Xbf, float* __restrict__ O) {
    const int b   = blockIdx.x & 7;          // batch -> XCD pinning
    const int qt  = blockIdx.x >> 3;         // 0..63
    const int tid = threadIdx.x;
    const int lane = tid & 63;
    const int w    = tid >> 6;
    const int col  = lane & 15;
    const int kgrp = lane >> 4;

    __shared__ alignas(16) unsigned short Klds[KB * DIM];       // 64 KB, swizzled
    __shared__ alignas(16) float Sbuf[QB][KB + 4];              // 8.7 KB
    __shared__ alignas(16) unsigned short Pfrag[2][2][64][8];   // 4 KB, A-frag layout
    __shared__ float m_s[QB], l_s[QB], fac_s[QB];

    const unsigned short* Xb = Xbf + (size_t)b * SEQ * DIM;

    // ---- Q preload: wave w owns 16 q-rows (strip qs = w>>2), kc strip = w&3
    const int qs = w >> 2;       // 0..1
    const int kc = w & 3;        // 0..3
    short8 qfrag[16];            // 64 VGPR, loaded directly as bf16
    {
        const int qrow = qt * QB + qs * 16 + col;
        const unsigned short* qp = Xb + (size_t)qrow * DIM;
        #pragma unroll
        for (int ks = 0; ks < 16; ++ks)
            qfrag[ks] = *(const short8*)(qp + ks * 32 + kgrp * 8);
    }

    if (tid < QB) { m_s[tid] = -INFINITY; l_s[tid] = 0.f; }

    f32x4 oacc[2][4];   // O[32 q][w*64 .. +64 d] : [q2][dt]
    #pragma unroll
    for (int i = 0; i < 2; ++i)
        #pragma unroll
        for (int j = 0; j < 4; ++j)
            oacc[i][j] = (f32x4){0.f, 0.f, 0.f, 0.f};

    for (int t = 0; t < NKV; ++t) {
        __syncthreads();   // (a) prev readers done
        // ---- stage KV tile (bf16 copy, swizzled). thread t: kv = t>>3,
        // d0 = i*64 + (t&7)*8 -> the 8 lanes of one kv row hit 8 distinct
        // bank-quads (i*64 elems == 0 mod 32 dwords would alias; (t&7)*8 doesn't).
        {
            const unsigned short* kp = Xb + (size_t)(t * KB) * DIM;
            const int kv = tid >> 3;
            const unsigned short* src = kp + (size_t)kv * DIM + (tid & 7) * 8;
            unsigned short* dst = &Klds[kv * DIM];
            const int sw = swz(kv);
            #pragma unroll
            for (int i = 0; i < 8; ++i) {
                const int d0 = i * 64 + (tid & 7) * 8;
                *(short8*)(dst + (d0 ^ sw)) = *(const short8*)(src + i * 64);
            }
        }
        __syncthreads();   // (b) tile ready

        // ---- QK^T: wave computes S[qs*16 .. +16][kc*16 .. +16]
        {
            const int kvrow = kc * 16 + col;
            const unsigned short* kbase = &Klds[kvrow * DIM];
            const int sw = swz(kvrow);
            f32x4 sacc = (f32x4){0.f,0.f,0.f,0.f};
            #pragma unroll
            for (int ks = 0; ks < 16; ++ks) {
                short8 kfr = *(const short8*)(kbase + ((ks * 32 + kgrp * 8) ^ sw));
                sacc = __builtin_amdgcn_mfma_f32_16x16x32_bf16(qfrag[ks], kfr, sacc, 0, 0, 0);
            }
            #pragma unroll
            for (int r = 0; r < 4; ++r)
                Sbuf[qs * 16 + kgrp * 4 + r][kc * 16 + col] = sacc[r];
        }
        __syncthreads();   // (c) Sbuf ready

        // ---- online softmax: 16 threads/row, 4 scores each
        {
            const int r = tid >> 4;     // 0..31
            const int c = tid & 15;     // 0..15
            float4 sa = *(const float4*)&Sbuf[r][c * 4];
            float mloc = fmaxf(fmaxf(sa.x, sa.y), fmaxf(sa.z, sa.w));
            mloc = fmaxf(mloc, __shfl_xor(mloc, 1));
            mloc = fmaxf(mloc, __shfl_xor(mloc, 2));
            mloc = fmaxf(mloc, __shfl_xor(mloc, 4));
            mloc = fmaxf(mloc, __shfl_xor(mloc, 8));
            const float mold = m_s[r];
            const float mnew = fmaxf(mold, mloc);
            const float fac  = __expf(mold - mnew);   // exp(-inf)=0 on first tile
            float p0 = __expf(sa.x - mnew), p1 = __expf(sa.y - mnew);
            float p2 = __expf(sa.z - mnew), p3 = __expf(sa.w - mnew);
            float lsum = (p0 + p1) + (p2 + p3);
            lsum += __shfl_xor(lsum, 1);
            lsum += __shfl_xor(lsum, 2);
            lsum += __shfl_xor(lsum, 4);
            lsum += __shfl_xor(lsum, 8);
            ushort4v p4;
            p4[0] = f2bf(p0); p4[1] = f2bf(p1); p4[2] = f2bf(p2); p4[3] = f2bf(p3);
            // value (q=r, kv=4c+jj) -> Pfrag[q>>4][kv>>5][(q&15)+16*((kv>>3)&3)][kv&7]
            *(ushort4v*)&Pfrag[r >> 4][c >> 3][(r & 15) + 16 * ((c >> 1) & 3)][(c & 1) * 4] = p4;
            if (c == 0) {
                m_s[r] = mnew;
                fac_s[r] = fac;
                l_s[r] = l_s[r] * fac + lsum;
            }
        }
        __syncthreads();   // (d) Pfrag/fac ready

        // ---- rescale O, then PV: A from Pfrag (lane-contig b128), B via gather
        #pragma unroll
        for (int q2 = 0; q2 < 2; ++q2) {
            #pragma unroll
            for (int r = 0; r < 4; ++r) {
                const float f = fac_s[q2 * 16 + kgrp * 4 + r];
                #pragma unroll
                for (int dt = 0; dt < 4; ++dt) oacc[q2][dt][r] *= f;
            }
        }
        #pragma unroll
        for (int kc2 = 0; kc2 < 2; ++kc2) {
            const int kvb = kc2 * 32 + kgrp * 8;
            short8 afr[2];
            #pragma unroll
            for (int q2 = 0; q2 < 2; ++q2)
                afr[q2] = *(const short8*)&Pfrag[q2][kc2][lane][0];
            #pragma unroll
            for (int dt = 0; dt < 4; ++dt) {
                const int d = w * 64 + dt * 16 + col;
                short8 bfr;
                #pragma unroll
                for (int j = 0; j < 8; ++j) {
                    const int kv = kvb + j;
                    bfr[j] = (short)Klds[kv * DIM + (d ^ swz(kv))];
                }
                #pragma unroll
                for (int q2 = 0; q2 < 2; ++q2)
                    oacc[q2][dt] = __builtin_amdgcn_mfma_f32_16x16x32_bf16(afr[q2], bfr, oacc[q2][dt], 0, 0, 0);
            }
        }
    }

    // ---- epilogue: divide by l, store fp32
    #pragma unroll
    for (int q2 = 0; q2 < 2; ++q2) {
        #pragma unroll
        for (int r = 0; r < 4; ++r) {
            const int row = q2 * 16 + kgrp * 4 + r;
            const float inv = 1.f / l_s[row];
            float* op = O + ((size_t)b * SEQ + qt * QB + row) * DIM + w * 64 + col;
            #pragma unroll
            for (int dt = 0; dt < 4; ++dt)
                op[dt * 16] = oacc[q2][dt][r] * inv;
        }
    }
}

extern "C" void kernel_launch(void* const* d_in, const int* in_sizes, int n_in,
                              void* d_out, int out_size, void* d_ws, size_t ws_size,
                              hipStream_t stream) {
    const float* X = (const float*)d_in[0];
    float* Out = (float*)d_out;
    unsigned short* Xbf = (unsigned short*)d_ws;   // 16.8 MB bf16 copy

    const int n8 = BATCH * SEQ * DIM / 8;          // 1,048,576
    hipLaunchKernelGGL(to_bf16_kernel, dim3(n8 / 256), dim3(256), 0, stream, X, Xbf, n8);

    dim3 grid(BATCH * (SEQ / QB));                 // 512 blocks -> 2 per CU
    dim3 block(NT);
    hipLaunchKernelGGL(attn_fwd, grid, block, 0, stream, Xbf, Out);
}